// Round 2
// baseline (104.090 us; speedup 1.0000x reference)
//
#include <hip/hip_runtime.h>

// MusicalConstraintLoss: tokens [B=512, S=16384] int32.
//   rhythm  = 0.01 * var(gaps between consecutive time tokens, ddof=1, pooled)
//   harmony = 0.1  * count(adjacent note pairs with |pc diff|==6) / (B*S)
//   voice   = count(consecutive-note leaps |dv|>12) / B
//   total   = rhythm + harmony + 0.5*voice
// Single fused kernel: per-row block scan -> per-row int32 partials -> flag
// (agent-scope release) -> last block (511) spin-acquires flags, reduces 512
// rows, computes final doubles. All per-row accumulators fit int32
// (max Sum d^2 per row = 16384^2 = 2.68e8 < 2^31); global sums widened to i64.

#define BATCH 512
#define SEQ   16384
#define TPB   1024
#define EPT   (SEQ / TPB)   // 16 contiguous elements per thread
#define NWAVES (TPB / 64)   // 16
#define SENTINEL 0x5A5AA55Au

__global__ __launch_bounds__(TPB) void
mcl_fused_kernel(const int* __restrict__ tokens,
                 int* __restrict__ ct_a, int* __restrict__ sd_a,
                 int* __restrict__ sd2_a, int* __restrict__ harm_a,
                 int* __restrict__ leap_a, unsigned* __restrict__ flags,
                 float* __restrict__ out)
{
    const int row  = blockIdx.x;
    const int t    = threadIdx.x;
    const int lane = t & 63;
    const int wave = t >> 6;

    __shared__ int s_first[TPB];          // halo: each thread's first element
    __shared__ int s_time[NWAVES];        // per-wave inclusive max last_time
    __shared__ int s_note[NWAVES];        // per-wave inclusive max note pack
    __shared__ long long s_red[NWAVES][5];

    const int* rowp = tokens + (size_t)row * SEQ;
    const int  base = t * EPT;

    // ---- load 16 contiguous ints via 4x int4 (64 B per lane) ----
    int e[EPT];
    const int4* v = (const int4*)(rowp + base);
#pragma unroll
    for (int j = 0; j < EPT / 4; ++j) {
        int4 x = v[j];
        e[4*j+0] = x.x; e[4*j+1] = x.y; e[4*j+2] = x.z; e[4*j+3] = x.w;
    }
    s_first[t] = e[0];
    __syncthreads();
    const int enext = (t + 1 < TPB) ? s_first[t + 1] : -1;  // row end: no pair

    // ---- local sequential scan, all-int32 accumulators ----
    int ct = 0, sd = 0, sd2 = 0, harm = 0, leaps = 0;
    int first_time = -1, last_time = -1;
    int first_note_val = -1, last_note_pos = -1, last_note_val = 0;

#pragma unroll
    for (int j = 0; j < EPT; ++j) {
        const int tok = e[j];
        const int pos = base + j;
        const bool is_time = (unsigned)(tok - 256) < 512u;  // [256,768)
        const bool is_note = (unsigned)tok < 128u;          // [0,128)
        if (is_time) {
            if (last_time >= 0) {
                const int d = pos - last_time;
                ct++; sd += d; sd2 += d * d;
            } else first_time = pos;
            last_time = pos;
        }
        if (is_note) {
            if (last_note_pos >= 0) {
                // leap iff |tok - last_note_val| > 12
                if ((unsigned)(tok - last_note_val + 12) > 24u) leaps++;
            } else first_note_val = tok;
            last_note_pos = pos; last_note_val = tok;
        }
        const int nb = (j < EPT - 1) ? e[j + 1] : enext;
        if (is_note && (unsigned)nb < 128u) {
            // tritone iff (tok - nb) == +-6 mod 12  <=>  (tok-nb+126) % 12 == 0
            const unsigned u = (unsigned)(tok - nb + 126);   // [0,253]
            const unsigned q = (u * 43691u) >> 19;           // u / 12
            if (q * 12u == u) harm++;
        }
    }

    // ---- block-wide exclusive max-scan: predecessor time pos / note pack ----
    int note_pack = (last_note_pos >= 0) ? ((last_note_pos << 10) | last_note_val) : -1;
    int lt = last_time, np = note_pack;
#pragma unroll
    for (int off = 1; off < 64; off <<= 1) {
        int a = __shfl_up(lt, off);
        int b = __shfl_up(np, off);
        if (lane >= off) { lt = max(lt, a); np = max(np, b); }
    }
    int excl_t = __shfl_up(lt, 1);
    int excl_n = __shfl_up(np, 1);
    if (lane == 0) { excl_t = -1; excl_n = -1; }
    if (lane == 63) { s_time[wave] = lt; s_note[wave] = np; }
    __syncthreads();
    int pt = -1, pn = -1;
    for (int w = 0; w < wave; ++w) {   // wave-uniform, <=15 iters
        pt = max(pt, s_time[w]);
        pn = max(pn, s_note[w]);
    }
    const int prev_time = max(pt, excl_t);
    const int prev_note = max(pn, excl_n);

    if (first_time >= 0 && prev_time >= 0) {
        const int d = first_time - prev_time;
        ct++; sd += d; sd2 += d * d;        // d^2 <= 16383^2, fits int32
    }
    if (first_note_val >= 0 && prev_note >= 0) {
        if ((unsigned)(first_note_val - (prev_note & 1023) + 12) > 24u) leaps++;
    }

    // ---- block reduce 5 int accumulators ----
#pragma unroll
    for (int off = 32; off; off >>= 1) {
        ct    += __shfl_down(ct, off);
        sd    += __shfl_down(sd, off);
        sd2   += __shfl_down(sd2, off);
        harm  += __shfl_down(harm, off);
        leaps += __shfl_down(leaps, off);
    }
    if (lane == 0) {
        s_red[wave][0] = ct;   s_red[wave][1] = sd;  s_red[wave][2] = sd2;
        s_red[wave][3] = harm; s_red[wave][4] = leaps;
    }
    __syncthreads();
    if (t == 0) {
        int a0 = 0, a1 = 0, a2 = 0, a3 = 0, a4 = 0;
        for (int w = 0; w < NWAVES; ++w) {
            a0 += (int)s_red[w][0]; a1 += (int)s_red[w][1]; a2 += (int)s_red[w][2];
            a3 += (int)s_red[w][3]; a4 += (int)s_red[w][4];
        }
        ct_a[row] = a0; sd_a[row] = a1; sd2_a[row] = a2;
        harm_a[row] = a3; leap_a[row] = a4;
        __threadfence();   // make partials agent-visible before flag
        __hip_atomic_store(&flags[row], SENTINEL, __ATOMIC_RELEASE,
                           __HIP_MEMORY_SCOPE_AGENT);
    }

    // ---- finalizer: last-dispatched block reduces all rows ----
    if (row == BATCH - 1) {
        if (t < BATCH) {
            while (__hip_atomic_load(&flags[t], __ATOMIC_ACQUIRE,
                                     __HIP_MEMORY_SCOPE_AGENT) != SENTINEL) {
                __builtin_amdgcn_s_sleep(4);
            }
        }
        __syncthreads();
        __threadfence();   // acquire: invalidate caches before partial reads

        long long v0 = 0, v1 = 0, v2 = 0, v3 = 0, v4 = 0;
        if (t < BATCH) {
            v0 = ct_a[t]; v1 = sd_a[t]; v2 = sd2_a[t];
            v3 = harm_a[t]; v4 = leap_a[t];
        }
#pragma unroll
        for (int off = 32; off; off >>= 1) {
            v0 += __shfl_down(v0, off);
            v1 += __shfl_down(v1, off);
            v2 += __shfl_down(v2, off);
            v3 += __shfl_down(v3, off);
            v4 += __shfl_down(v4, off);
        }
        __syncthreads();   // s_red reuse
        if (lane == 0) {
            s_red[wave][0] = v0; s_red[wave][1] = v1; s_red[wave][2] = v2;
            s_red[wave][3] = v3; s_red[wave][4] = v4;
        }
        __syncthreads();
        if (t == 0) {
            long long A = 0, Bs = 0, C = 0, D = 0, E = 0;
            for (int w = 0; w < NWAVES; ++w) {
                A += s_red[w][0]; Bs += s_red[w][1]; C += s_red[w][2];
                D += s_red[w][3]; E += s_red[w][4];
            }
            const double n = (double)A;
            double rhythm = 0.0;
            if (A > 1) {
                const double ss = (double)C - ((double)Bs * (double)Bs) / n;
                rhythm = 0.01 * ss / (n - 1.0);
            }
            const double harmony = 0.1 * (double)D / ((double)BATCH * (double)SEQ);
            const double voice   = (double)E / (double)BATCH;
            out[0] = (float)rhythm;
            out[1] = (float)harmony;
            out[2] = (float)voice;
            out[3] = (float)(rhythm + harmony + 0.5 * voice);
        }
    }
}

extern "C" void kernel_launch(void* const* d_in, const int* in_sizes, int n_in,
                              void* d_out, int out_size, void* d_ws, size_t ws_size,
                              hipStream_t stream)
{
    const int* tokens = (const int*)d_in[0];
    float* out = (float*)d_out;

    char* ws = (char*)d_ws;
    int*      ct_a   = (int*)ws;                 // 2048 B
    int*      sd_a   = (int*)(ws + 2048);        // 2048 B
    int*      sd2_a  = (int*)(ws + 4096);        // 2048 B
    int*      harm_a = (int*)(ws + 6144);        // 2048 B
    int*      leap_a = (int*)(ws + 8192);        // 2048 B
    unsigned* flags  = (unsigned*)(ws + 10240);  // 2048 B

    mcl_fused_kernel<<<BATCH, TPB, 0, stream>>>(tokens, ct_a, sd_a, sd2_a,
                                                harm_a, leap_a, flags, out);
}

// Round 3
// 82.266 us; speedup vs baseline: 1.2653x; 1.2653x over previous
//
#include <hip/hip_runtime.h>

// MusicalConstraintLoss: tokens [B=512, S=16384] int32.
//   rhythm  = 0.01 * var(gaps between consecutive time tokens, ddof=1, pooled)
//   harmony = 0.1  * count(adjacent note pairs with |pc diff|==6) / (B*S)
//   voice   = count(consecutive-note leaps |dv|>12) / B
//   total   = rhythm + harmony + 0.5*voice
//
// R3: two-kernel structure (no fences/spin — kernel boundary gives visibility).
// Coalesced global loads (lane-contiguous int4, 1 KB/wave/instr) staged through
// padded LDS (+1 dword per 16 -> thread read stride 17, conflict-free), then
// per-thread contiguous scan of 16 elements. ct/sd computed by telescoping
// (count of time tokens, first/last position) instead of per-element adds.
// All per-row accumulators fit int32 (max sum d^2 = 16383^2 ~ 2.7e8).

#define BATCH 512
#define SEQ   16384
#define TPB   1024
#define EPT   (SEQ / TPB)    // 16 contiguous elements per thread
#define NWAVES (TPB / 64)    // 16
#define LDS_DW (SEQ + (SEQ >> 4) + 1)   // 17409 dwords, ~68 KiB -> 2 blocks/CU

__global__ __launch_bounds__(TPB) void
mcl_scan_kernel(const int* __restrict__ tokens,
                int* __restrict__ ct_a, int* __restrict__ sd_a,
                int* __restrict__ sd2_a, int* __restrict__ harm_a,
                int* __restrict__ leap_a)
{
    const int row  = blockIdx.x;
    const int t    = threadIdx.x;
    const int lane = t & 63;
    const int wave = t >> 6;

    __shared__ int s_tok[LDS_DW];
    __shared__ int s_time[NWAVES];       // per-wave inclusive max last_time
    __shared__ int s_note[NWAVES];       // per-wave inclusive max note pack
    __shared__ int s_red[NWAVES][6];

    const int4* v4 = (const int4*)(tokens + (size_t)row * SEQ);

    // ---- coalesced load: lane-contiguous int4 (1 KB per wave-instr) ----
    int4 x[4];
#pragma unroll
    for (int c = 0; c < 4; ++c) x[c] = v4[c * TPB + t];
#pragma unroll
    for (int c = 0; c < 4; ++c) {
        const int u = c * TPB + t;                     // int4 unit index
        const int bdw = 17 * (u >> 2) + 4 * (u & 3);   // padded dword addr
        s_tok[bdw + 0] = x[c].x; s_tok[bdw + 1] = x[c].y;
        s_tok[bdw + 2] = x[c].z; s_tok[bdw + 3] = x[c].w;
    }
    __syncthreads();

    // ---- per-thread scan of contiguous 16 elements (LDS stride 17) ----
    const int rbase = 17 * t;
    int n_time = 0, sd2 = 0, harm = 0, leaps = 0;
    int first_time = 0x7FFFFFFF, last_time = -1;
    int first_note_val = -1, last_note_pos = -1, last_note_val = 0;

#pragma unroll
    for (int j = 0; j < EPT; ++j) {
        const int tok = s_tok[rbase + j];
        const int pos = (t << 4) + j;
        const bool is_time = (unsigned)(tok - 256) < 512u;  // [256,768)
        const bool is_note = (unsigned)tok < 128u;          // [0,128)
        if (is_time) {
            if (last_time >= 0) {
                const int d = pos - last_time;
                sd2 += d * d;
            } else first_time = pos;
            last_time = pos;
            n_time++;
        }
        if (is_note) {
            if (last_note_pos >= 0) {
                if ((unsigned)(tok - last_note_val + 12) > 24u) leaps++;  // |dv|>12
            } else first_note_val = tok;
            last_note_pos = pos; last_note_val = tok;
        }
        // neighbor: j<15 in-segment; j==15 -> next segment's first (17 ahead)
        const int nb = (j < EPT - 1) ? s_tok[rbase + j + 1]
                                     : ((t < TPB - 1) ? s_tok[rbase + 17] : -1);
        if (is_note && (unsigned)nb < 128u) {
            // tritone iff (tok - nb) == 6 (mod 12) <=> (tok-nb+126) % 12 == 0
            const unsigned u = (unsigned)(tok - nb + 126);   // [0,253]
            const unsigned q = (u * 43691u) >> 19;           // u / 12
            if (q * 12u == u) harm++;
        }
    }

    // ---- block-wide exclusive max-scan: predecessor time pos / note pack ----
    int note_pack = (last_note_pos >= 0) ? ((last_note_pos << 10) | last_note_val) : -1;
    int lt = last_time, np = note_pack;
#pragma unroll
    for (int off = 1; off < 64; off <<= 1) {
        int a = __shfl_up(lt, off);
        int b = __shfl_up(np, off);
        if (lane >= off) { lt = max(lt, a); np = max(np, b); }
    }
    int excl_t = __shfl_up(lt, 1);
    int excl_n = __shfl_up(np, 1);
    if (lane == 0) { excl_t = -1; excl_n = -1; }
    if (lane == 63) { s_time[wave] = lt; s_note[wave] = np; }
    __syncthreads();
    int pt = -1, pn = -1;
    for (int w = 0; w < wave; ++w) {   // wave-uniform, <=15 iters
        pt = max(pt, s_time[w]);
        pn = max(pn, s_note[w]);
    }
    const int prev_time = max(pt, excl_t);
    const int prev_note = max(pn, excl_n);

    if (first_time != 0x7FFFFFFF && prev_time >= 0) {
        const int d = first_time - prev_time;       // cross-boundary gap
        sd2 += d * d;
    }
    if (first_note_val >= 0 && prev_note >= 0) {
        if ((unsigned)(first_note_val - (prev_note & 1023) + 12) > 24u) leaps++;
    }

    // ---- block reduce: sums + min(first_time) ----
#pragma unroll
    for (int off = 32; off; off >>= 1) {
        n_time += __shfl_down(n_time, off);
        sd2    += __shfl_down(sd2, off);
        harm   += __shfl_down(harm, off);
        leaps  += __shfl_down(leaps, off);
        first_time = min(first_time, __shfl_down(first_time, off));
    }
    if (lane == 0) {
        s_red[wave][0] = n_time; s_red[wave][1] = sd2;
        s_red[wave][2] = harm;   s_red[wave][3] = leaps;
        s_red[wave][4] = first_time;
    }
    __syncthreads();
    if (t == 0) {
        int a0 = 0, a1 = 0, a2 = 0, a3 = 0, fmin = 0x7FFFFFFF, lmax = -1;
        for (int w = 0; w < NWAVES; ++w) {
            a0 += s_red[w][0]; a1 += s_red[w][1];
            a2 += s_red[w][2]; a3 += s_red[w][3];
            fmin = min(fmin, s_red[w][4]);
            lmax = max(lmax, s_time[w]);     // row's last time-token position
        }
        // telescoping: #gaps = n_time - 1; sum(gaps) = last - first
        ct_a[row]   = (a0 > 0) ? (a0 - 1) : 0;
        sd_a[row]   = (a0 > 0) ? (lmax - fmin) : 0;
        sd2_a[row]  = a1;
        harm_a[row] = a2;
        leap_a[row] = a3;
    }
}

__global__ __launch_bounds__(512) void
mcl_final_kernel(const int* __restrict__ ct_a, const int* __restrict__ sd_a,
                 const int* __restrict__ sd2_a, const int* __restrict__ harm_a,
                 const int* __restrict__ leap_a, float* __restrict__ out)
{
    const int t = threadIdx.x;
    const int lane = t & 63, wave = t >> 6;
    long long v0 = ct_a[t], v1 = sd_a[t], v2 = sd2_a[t];
    long long v3 = harm_a[t], v4 = leap_a[t];
#pragma unroll
    for (int off = 32; off; off >>= 1) {
        v0 += __shfl_down(v0, off);
        v1 += __shfl_down(v1, off);
        v2 += __shfl_down(v2, off);
        v3 += __shfl_down(v3, off);
        v4 += __shfl_down(v4, off);
    }
    __shared__ long long s[8][5];
    if (lane == 0) { s[wave][0]=v0; s[wave][1]=v1; s[wave][2]=v2; s[wave][3]=v3; s[wave][4]=v4; }
    __syncthreads();
    if (t == 0) {
        long long A = 0, Bs = 0, C = 0, D = 0, E = 0;
        for (int w = 0; w < 8; ++w) { A+=s[w][0]; Bs+=s[w][1]; C+=s[w][2]; D+=s[w][3]; E+=s[w][4]; }
        const double n = (double)A;
        double rhythm = 0.0;
        if (A > 1) {
            const double ss = (double)C - ((double)Bs * (double)Bs) / n;
            rhythm = 0.01 * ss / (n - 1.0);
        }
        const double harmony = 0.1 * (double)D / ((double)BATCH * (double)SEQ);
        const double voice   = (double)E / (double)BATCH;
        out[0] = (float)rhythm;
        out[1] = (float)harmony;
        out[2] = (float)voice;
        out[3] = (float)(rhythm + harmony + 0.5 * voice);
    }
}

extern "C" void kernel_launch(void* const* d_in, const int* in_sizes, int n_in,
                              void* d_out, int out_size, void* d_ws, size_t ws_size,
                              hipStream_t stream)
{
    const int* tokens = (const int*)d_in[0];
    float* out = (float*)d_out;

    char* ws = (char*)d_ws;
    int* ct_a   = (int*)ws;                 // 2048 B
    int* sd_a   = (int*)(ws + 2048);        // 2048 B
    int* sd2_a  = (int*)(ws + 4096);        // 2048 B
    int* harm_a = (int*)(ws + 6144);        // 2048 B
    int* leap_a = (int*)(ws + 8192);        // 2048 B

    mcl_scan_kernel<<<BATCH, TPB, 0, stream>>>(tokens, ct_a, sd_a, sd2_a, harm_a, leap_a);
    mcl_final_kernel<<<1, 512, 0, stream>>>(ct_a, sd_a, sd2_a, harm_a, leap_a, out);
}

// Round 4
// 82.248 us; speedup vs baseline: 1.2656x; 1.0002x over previous
//
#include <hip/hip_runtime.h>

// MusicalConstraintLoss: tokens [B=512, S=16384] int32.
//   rhythm  = 0.01 * var(gaps between consecutive time tokens, ddof=1, pooled)
//   harmony = 0.1  * count(adjacent note pairs with |pc diff|==6) / (B*S)
//   voice   = count(consecutive-note leaps |dv|>12) / B
//   total   = rhythm + harmony + 0.5*voice
//
// R4: 2048 blocks x 256 threads — one 4096-token segment per block (4 segs/row).
// Narrow barriers (4 waves), 8 blocks/CU (32 waves, full occupancy, 139 KB LDS).
// Per-segment summaries (8 ints) written to ws; finalize kernel stitches the 4
// segments of each row sequentially (boundary gap^2 / boundary leap), then
// reduces 512 rows and computes the scalars in double. Exact integer math.

#define BATCH 512
#define SEQ   16384
#define TPB   256
#define EPT   16
#define SEG   (TPB * EPT)          // 4096 tokens per block
#define SEGS  (SEQ / SEG)          // 4 segments per row
#define NWAVES (TPB / 64)          // 4
#define LDS_DW (SEG + (SEG >> 4) + 1)   // 4353 dwords ~= 17.4 KB

__global__ __launch_bounds__(TPB) void
mcl_scan_kernel(const int* __restrict__ tokens, int* __restrict__ seg_out)
{
    const int blk  = blockIdx.x;
    const int row  = blk >> 2;
    const int seg  = blk & 3;
    const int t    = threadIdx.x;
    const int lane = t & 63;
    const int wave = t >> 6;

    __shared__ int s_tok[LDS_DW];
    __shared__ int s_halo;                 // first token of next segment (-1 at row end)
    __shared__ int s_time[NWAVES];         // per-wave inclusive max last_time
    __shared__ int s_note[NWAVES];         // per-wave inclusive max note pack
    __shared__ int s_red[NWAVES][8];

    const int* rowp  = tokens + (size_t)row * SEQ;
    const int  gbase = seg * SEG;          // segment start (global pos in row)
    const int4* v4   = (const int4*)(rowp + gbase);

    // ---- coalesced load: lane-contiguous int4 -> padded LDS ----
    int4 x[4];
#pragma unroll
    for (int c = 0; c < 4; ++c) x[c] = v4[c * TPB + t];
    if (t == 0) s_halo = (seg < SEGS - 1) ? rowp[gbase + SEG] : -1;
#pragma unroll
    for (int c = 0; c < 4; ++c) {
        const int u   = c * TPB + t;                   // int4 unit index
        const int bdw = 17 * (u >> 2) + 4 * (u & 3);   // padded dword addr
        s_tok[bdw + 0] = x[c].x; s_tok[bdw + 1] = x[c].y;
        s_tok[bdw + 2] = x[c].z; s_tok[bdw + 3] = x[c].w;
    }
    __syncthreads();

    // ---- per-thread scan of contiguous 16 elements (LDS stride 17) ----
    const int rbase = 17 * t;
    const int pbase = gbase + (t << 4);
    int n_time = 0, sd2 = 0, harm = 0, leaps = 0;
    int first_time = 0x7FFFFFFF, last_time = -1;
    int first_note_pack = 0x7FFFFFFF;      // (pos<<10)|val of first note
    int last_note_pos = -1, last_note_val = 0;

#pragma unroll
    for (int j = 0; j < EPT; ++j) {
        const int tok = s_tok[rbase + j];
        const int pos = pbase + j;
        const bool is_time = (unsigned)(tok - 256) < 512u;  // [256,768)
        const bool is_note = (unsigned)tok < 128u;          // [0,128)
        if (is_time) {
            if (last_time >= 0) {
                const int d = pos - last_time;
                sd2 += d * d;
            } else first_time = pos;
            last_time = pos;
            n_time++;
        }
        if (is_note) {
            if (last_note_pos >= 0) {
                if ((unsigned)(tok - last_note_val + 12) > 24u) leaps++;  // |dv|>12
            } else first_note_pack = (pos << 10) | tok;
            last_note_pos = pos; last_note_val = tok;
        }
        const int nb = (j < EPT - 1) ? s_tok[rbase + j + 1]
                     : ((t < TPB - 1) ? s_tok[rbase + 17] : s_halo);
        if (is_note && (unsigned)nb < 128u) {
            // tritone iff (tok - nb) == +-6 mod 12 <=> (tok-nb+126) % 12 == 0
            const unsigned u = (unsigned)(tok - nb + 126);   // [0,253]
            const unsigned q = (u * 43691u) >> 19;           // u / 12
            if (q * 12u == u) harm++;
        }
    }

    // ---- block-wide exclusive max-scan: in-segment predecessor ----
    int note_pack = (last_note_pos >= 0) ? ((last_note_pos << 10) | last_note_val) : -1;
    int lt = last_time, np = note_pack;
#pragma unroll
    for (int off = 1; off < 64; off <<= 1) {
        int a = __shfl_up(lt, off);
        int b = __shfl_up(np, off);
        if (lane >= off) { lt = max(lt, a); np = max(np, b); }
    }
    int excl_t = __shfl_up(lt, 1);
    int excl_n = __shfl_up(np, 1);
    if (lane == 0) { excl_t = -1; excl_n = -1; }
    if (lane == 63) { s_time[wave] = lt; s_note[wave] = np; }
    __syncthreads();
    int pt = -1, pn = -1;
    for (int w = 0; w < wave; ++w) {   // wave-uniform, <=3 iters
        pt = max(pt, s_time[w]);
        pn = max(pn, s_note[w]);
    }
    const int prev_time = max(pt, excl_t);
    const int prev_note = max(pn, excl_n);

    if (first_time != 0x7FFFFFFF && prev_time >= 0) {
        const int d = first_time - prev_time;     // in-segment boundary gap
        sd2 += d * d;
    }
    if (first_note_pack != 0x7FFFFFFF && prev_note >= 0) {
        if ((unsigned)((first_note_pack & 1023) - (prev_note & 1023) + 12) > 24u) leaps++;
    }

    // ---- block reduce -> segment summary (8 ints) ----
#pragma unroll
    for (int off = 32; off; off >>= 1) {
        n_time += __shfl_down(n_time, off);
        sd2    += __shfl_down(sd2, off);
        harm   += __shfl_down(harm, off);
        leaps  += __shfl_down(leaps, off);
        first_time      = min(first_time, __shfl_down(first_time, off));
        first_note_pack = min(first_note_pack, __shfl_down(first_note_pack, off));
    }
    if (lane == 0) {
        s_red[wave][0] = n_time; s_red[wave][1] = sd2;
        s_red[wave][2] = harm;   s_red[wave][3] = leaps;
        s_red[wave][4] = first_time;
        s_red[wave][5] = first_note_pack;
    }
    __syncthreads();
    if (t == 0) {
        int a0 = 0, a1 = 0, a2 = 0, a3 = 0;
        int ftm = 0x7FFFFFFF, fnp = 0x7FFFFFFF, ltm = -1, lnp = -1;
        for (int w = 0; w < NWAVES; ++w) {
            a0 += s_red[w][0]; a1 += s_red[w][1];
            a2 += s_red[w][2]; a3 += s_red[w][3];
            ftm = min(ftm, s_red[w][4]);
            fnp = min(fnp, s_red[w][5]);
            ltm = max(ltm, s_time[w]);     // segment last time pos
            lnp = max(lnp, s_note[w]);     // segment last note pack
        }
        int* o = seg_out + blk * 8;
        o[0] = a0; o[1] = a1; o[2] = a2; o[3] = a3;
        o[4] = ftm; o[5] = ltm; o[6] = fnp; o[7] = lnp;
    }
}

__global__ __launch_bounds__(512) void
mcl_final_kernel(const int* __restrict__ seg_out, float* __restrict__ out)
{
    const int t = threadIdx.x;          // one row per thread
    const int lane = t & 63, wave = t >> 6;

    // ---- stitch the row's 4 segments sequentially ----
    const int* p = seg_out + t * (SEGS * 8);
    int n_time = 0, sd2 = 0, harm = 0, leaps = 0;
    int run_last_t = -1, run_last_np = -1;
    int row_first_t = 0x7FFFFFFF;
#pragma unroll
    for (int s = 0; s < SEGS; ++s) {
        const int nt  = p[s*8+0], s2  = p[s*8+1];
        const int hm  = p[s*8+2], lp  = p[s*8+3];
        const int ftm = p[s*8+4], ltm = p[s*8+5];
        const int fnp = p[s*8+6], lnp = p[s*8+7];
        n_time += nt; sd2 += s2; harm += hm; leaps += lp;
        if (nt > 0) {
            if (run_last_t >= 0) {
                const int d = ftm - run_last_t;     // cross-segment gap
                sd2 += d * d;
            } else row_first_t = ftm;
            run_last_t = ltm;
        }
        if (fnp != 0x7FFFFFFF) {
            if (run_last_np >= 0) {
                if ((unsigned)((fnp & 1023) - (run_last_np & 1023) + 12) > 24u) leaps++;
            }
            run_last_np = lnp;
        }
    }
    long long v0 = (n_time > 0) ? (n_time - 1) : 0;            // gap count
    long long v1 = (n_time > 0) ? (run_last_t - row_first_t) : 0;  // sum of gaps
    long long v2 = sd2, v3 = harm, v4 = leaps;

    // ---- reduce 512 rows ----
#pragma unroll
    for (int off = 32; off; off >>= 1) {
        v0 += __shfl_down(v0, off);
        v1 += __shfl_down(v1, off);
        v2 += __shfl_down(v2, off);
        v3 += __shfl_down(v3, off);
        v4 += __shfl_down(v4, off);
    }
    __shared__ long long s[8][5];
    if (lane == 0) { s[wave][0]=v0; s[wave][1]=v1; s[wave][2]=v2; s[wave][3]=v3; s[wave][4]=v4; }
    __syncthreads();
    if (t == 0) {
        long long A = 0, Bs = 0, C = 0, D = 0, E = 0;
        for (int w = 0; w < 8; ++w) { A+=s[w][0]; Bs+=s[w][1]; C+=s[w][2]; D+=s[w][3]; E+=s[w][4]; }
        const double n = (double)A;
        double rhythm = 0.0;
        if (A > 1) {
            const double ss = (double)C - ((double)Bs * (double)Bs) / n;
            rhythm = 0.01 * ss / (n - 1.0);
        }
        const double harmony = 0.1 * (double)D / ((double)BATCH * (double)SEQ);
        const double voice   = (double)E / (double)BATCH;
        out[0] = (float)rhythm;
        out[1] = (float)harmony;
        out[2] = (float)voice;
        out[3] = (float)(rhythm + harmony + 0.5 * voice);
    }
}

extern "C" void kernel_launch(void* const* d_in, const int* in_sizes, int n_in,
                              void* d_out, int out_size, void* d_ws, size_t ws_size,
                              hipStream_t stream)
{
    const int* tokens = (const int*)d_in[0];
    float* out = (float*)d_out;
    int* seg_out = (int*)d_ws;     // 2048 segments * 8 ints = 64 KB

    mcl_scan_kernel<<<BATCH * SEGS, TPB, 0, stream>>>(tokens, seg_out);
    mcl_final_kernel<<<1, BATCH, 0, stream>>>(seg_out, out);
}